// Round 2
// baseline (3718.102 us; speedup 1.0000x reference)
//
#include <hip/hip_runtime.h>
#include <stdint.h>

// Problem constants (DecoderLSTM): VOCAB=50257, E=H=512, B=32, S=512
// ALL float tensors are fp32 (reference uses jnp.float32); sequence is int32.
// Internally we run bf16 MFMA (convert on the fly); output is fp32.
#define EDIM  512
#define HDIM  512
#define BSZ   32
#define SLEN  512
#define GDIM  2048   // 4*H
#define GWG   32     // number of scan workgroups (h-column split)

typedef __bf16 bf16x8 __attribute__((ext_vector_type(8)));
typedef float  f32x4  __attribute__((ext_vector_type(4)));

__device__ __forceinline__ uint16_t f2bf(float f) {
  union { float f; uint32_t i; } v; v.f = f;
  uint32_t r = v.i + 0x7FFFu + ((v.i >> 16) & 1u);  // RNE
  return (uint16_t)(r >> 16);
}
__device__ __forceinline__ float bf2f(uint32_t u) {
  union { uint32_t i; float f; } v; v.i = u << 16; return v.f;
}
union BF8 { uint16_t u[8]; uint4 v; bf16x8 b; };
__device__ __forceinline__ uint4 pack8(float4 lo, float4 hi) {
  BF8 r;
  r.u[0] = f2bf(lo.x); r.u[1] = f2bf(lo.y); r.u[2] = f2bf(lo.z); r.u[3] = f2bf(lo.w);
  r.u[4] = f2bf(hi.x); r.u[5] = f2bf(hi.y); r.u[6] = f2bf(hi.z); r.u[7] = f2bf(hi.w);
  return r.v;
}
__device__ __forceinline__ float sigm(float x) { return 1.0f / (1.0f + __expf(-x)); }
__device__ __forceinline__ float tanh_(float x) {
  float ax = fabsf(x);
  float e  = __expf(2.0f * ax);          // overflow-safe: e=inf -> t=1
  float t  = 1.0f - 2.0f / (e + 1.0f);
  return copysignf(t, x);
}

// ---------------------------------------------------------------------------
// K1: const[g][b] = sum_k W_hh[g][k]*h0[b][k] + b_ih[g] + b_hh[g] (all fp32);
// also zeroes the barrier counter.
// ---------------------------------------------------------------------------
__global__ __launch_bounds__(256) void k_const(
    const float* __restrict__ Whh, const float* __restrict__ h0,
    const float* __restrict__ bih, const float* __restrict__ bhh,
    float* __restrict__ cgb, unsigned* __restrict__ ctr)
{
  int idx = blockIdx.x * 256 + threadIdx.x;        // 2048*32 = 65536
  if (idx == 0) *ctr = 0u;
  int g = idx >> 5, b = idx & 31;
  const float4* w4 = (const float4*)(Whh + (size_t)g * HDIM);
  const float4* h4 = (const float4*)(h0  + (size_t)b * HDIM);
  float acc = 0.f;
  #pragma unroll 8
  for (int k = 0; k < HDIM / 4; k++) {
    float4 a = w4[k], c = h4[k];
    acc += a.x * c.x + a.y * c.y + a.z * c.z + a.w * c.w;
  }
  acc += bih[g] + bhh[g];
  cgb[idx] = acc;   // layout [g][b]
}

// ---------------------------------------------------------------------------
// K2: eg[s][g][b] (bf16) = sum_e emb_table[seq[b][s]][e] * W_ih[g][e] + const[g][b]
// Per WG: 64 gate rows (bf16, frag-order, 64KB LDS) x 4 s values.
// MFMA 16x16x32_bf16: A = W_e chunk (M=g), B = gathered emb rows (N=b).
// ---------------------------------------------------------------------------
__global__ __launch_bounds__(256) void k_emb(
    const int* __restrict__ seq, const float* __restrict__ emb,
    const float* __restrict__ Wih, const float* __restrict__ cgb,
    uint16_t* __restrict__ eg)
{
  __shared__ uint4 wlds[4096];   // 64KB bf16, frag-order: [T=n>>4][kc][nl=n&15][q]
  const int tid = threadIdx.x;
  const int gc  = blockIdx.x & 31;   // 32 g-chunks of 64 rows
  const int sc  = blockIdx.x >> 5;   // 128 s-chunks of 4
  const int g0  = gc * 64, s0 = sc * 4;

  for (int i = tid; i < 64 * 64; i += 256) {       // 64 rows x 64 8-elem chunks
    int n = i >> 6, c = i & 63;
    const float* wp = Wih + (size_t)(g0 + n) * 1024 + c * 8;   // W_e = W_ih[:, :512]
    float4 lo = *(const float4*)(wp);
    float4 hi = *(const float4*)(wp + 4);
    wlds[(((n >> 4) * 16 + (c >> 2)) << 6) + ((n & 15) << 2) + (c & 3)] = pack8(lo, hi);
  }
  __syncthreads();

  const int lane = tid & 63, w = tid >> 6;
  const int q = lane >> 4, nl = lane & 15;
  const int Nt  = w & 1;            // b-tile
  const int Mt0 = (w >> 1) * 2;     // g-tile pair {Mt0, Mt0+1}
  const int bcol = Nt * 16 + nl;

  float c0i[4], c1i[4];             // baked const, fixed across s
  #pragma unroll
  for (int r = 0; r < 4; r++) {
    c0i[r] = cgb[(g0 + (Mt0    ) * 16 + q * 4 + r) * 32 + bcol];
    c1i[r] = cgb[(g0 + (Mt0 + 1) * 16 + q * 4 + r) * 32 + bcol];
  }

  for (int si = 0; si < 4; si++) {
    int s = s0 + si;
    int rowi = seq[bcol * SLEN + s];                 // gather index for this lane's b
    const float* brow = emb + (size_t)rowi * EDIM + q * 8;
    f32x4 acc0, acc1;
    #pragma unroll
    for (int r = 0; r < 4; r++) { acc0[r] = c0i[r]; acc1[r] = c1i[r]; }
    #pragma unroll 4
    for (int kc = 0; kc < 16; kc++) {
      float4 blo = *(const float4*)(brow + kc * 32);
      float4 bhi = *(const float4*)(brow + kc * 32 + 4);
      BF8 bf; bf.v = pack8(blo, bhi);
      BF8 a0; a0.v = wlds[(((Mt0    ) * 16 + kc) << 6) + (nl << 2) + q];
      BF8 a1; a1.v = wlds[(((Mt0 + 1) * 16 + kc) << 6) + (nl << 2) + q];
      acc0 = __builtin_amdgcn_mfma_f32_16x16x32_bf16(a0.b, bf.b, acc0, 0, 0, 0);
      acc1 = __builtin_amdgcn_mfma_f32_16x16x32_bf16(a1.b, bf.b, acc1, 0, 0, 0);
    }
    #pragma unroll
    for (int r = 0; r < 4; r++) {
      int m0 = (Mt0    ) * 16 + q * 4 + r;
      int m1 = (Mt0 + 1) * 16 + q * 4 + r;
      eg[((size_t)s * GDIM + g0 + m0) * 32 + bcol] = f2bf(acc0[r]);
      eg[((size_t)s * GDIM + g0 + m1) * 32 + bcol] = f2bf(acc1[r]);
    }
  }
}

// ---------------------------------------------------------------------------
// K3: sequential scan. 32 WGs x 128 threads, persistent; WG wg owns j-columns
// [wg*16, wg*16+16) of h for ALL 4 gates and ALL 32 batches. W_h slice (64
// rows x 512, bf16) in 64KB LDS in fragment order. h_{t-1} from a global
// bf16 ping-pong buffer; per-step barrier = monotonic agent-scope counter.
// Gate combine IN-LANE: acc[0..3]=i,f,g,o tiles share (lane,reg)=(jj,b).
// ---------------------------------------------------------------------------
__global__ __launch_bounds__(128) void k_scan(
    const float* __restrict__ Wih, const float* __restrict__ c0,
    const uint16_t* __restrict__ eg, uint16_t* __restrict__ hbuf,
    float* __restrict__ out, unsigned* __restrict__ ctr)
{
  __shared__ uint4 wlds[4096];   // 64KB
  const int tid = threadIdx.x;
  const int wg  = blockIdx.x;
  const int j0  = wg * 16;

  // Stage W_h slice: row n: gate=n>>4, jj=n&15 -> W_ih row gate*512+j0+jj, cols [512,1024)
  for (int i = tid; i < 64 * 64; i += 128) {
    int n = i >> 6, c = i & 63;
    int grow = (n >> 4) * HDIM + j0 + (n & 15);
    const float* wp = Wih + (size_t)grow * 1024 + 512 + c * 8;
    float4 lo = *(const float4*)(wp);
    float4 hi = *(const float4*)(wp + 4);
    wlds[(((n >> 4) * 16 + (c >> 2)) << 6) + ((n & 15) << 2) + (c & 3)] = pack8(lo, hi);
  }

  const int lane = tid & 63, w = tid >> 6;   // w = b-half (M-tile)
  const int q = lane >> 4, jj = lane & 15;   // jj = output j column (C col)
  const int b0 = w * 16 + q * 4;             // C rows: b0..b0+3
  float c0r[4];
  #pragma unroll
  for (int r = 0; r < 4; r++) c0r[r] = c0[(size_t)(b0 + r) * HDIM + j0 + jj];
  __syncthreads();

  for (int t = 0; t < SLEN; t++) {
    // eg loads first: independent of h, latency overlaps the barrier spin
    ushort4 egv[4];
    #pragma unroll
    for (int nt = 0; nt < 4; nt++)
      egv[nt] = *(const ushort4*)(eg + ((size_t)t * GDIM + nt * HDIM + j0 + jj) * 32 + b0);

    if (t > 0) {
      if (tid == 0) {
        unsigned target = (unsigned)(GWG * t);
        while (__hip_atomic_load(ctr, __ATOMIC_RELAXED, __HIP_MEMORY_SCOPE_AGENT) < target) {}
        (void)__hip_atomic_load(ctr, __ATOMIC_ACQUIRE, __HIP_MEMORY_SCOPE_AGENT); // inv caches
      }
      __syncthreads();
    }

    f32x4 acc[4];
    #pragma unroll
    for (int nt = 0; nt < 4; nt++) {
      acc[nt][0] = bf2f(egv[nt].x); acc[nt][1] = bf2f(egv[nt].y);
      acc[nt][2] = bf2f(egv[nt].z); acc[nt][3] = bf2f(egv[nt].w);
    }

    if (t > 0) {
      const uint16_t* hp = hbuf + ((t - 1) & 1) * (BSZ * HDIM)
                         + (size_t)(w * 16 + jj) * HDIM + q * 8;  // A[m=jj][k=q*8+j]
      #pragma unroll 4
      for (int kc = 0; kc < 16; kc++) {
        BF8 af; af.v = *(const uint4*)(hp + kc * 32);
        #pragma unroll
        for (int nt = 0; nt < 4; nt++) {
          BF8 bfr; bfr.v = wlds[((nt * 16 + kc) << 6) + (jj << 2) + q];
          acc[nt] = __builtin_amdgcn_mfma_f32_16x16x32_bf16(af.b, bfr.b, acc[nt], 0, 0, 0);
        }
      }
    }

    uint16_t* hw = hbuf + (t & 1) * (BSZ * HDIM);
    #pragma unroll
    for (int r = 0; r < 4; r++) {
      float i_ = sigm(acc[0][r]);
      float f_ = sigm(acc[1][r]);
      float g_ = tanh_(acc[2][r]);
      float o_ = sigm(acc[3][r]);
      float cn = f_ * c0r[r] + i_ * g_;       // cell NOT carried: always c0
      float hn = o_ * tanh_(cn);
      hw[(size_t)(b0 + r) * HDIM + j0 + jj] = f2bf(hn);
      out[(size_t)(b0 + r) * (SLEN * HDIM) + (size_t)t * HDIM + j0 + jj] = hn;
    }

    __syncthreads();   // all waves' stores issued before the release-add
    if (tid == 0)
      __hip_atomic_fetch_add(ctr, 1u, __ATOMIC_RELEASE, __HIP_MEMORY_SCOPE_AGENT);
  }
}

// ---------------------------------------------------------------------------
// Workspace layout (~67.5 MB):
//   [0,       262144)   const[g][b] f32
//   [262144,  262148)   barrier counter
//   [262400, +64MiB)    eg[s][g][b] bf16 (const baked in)
//   then 2 x 32KB h ping-pong (bf16)
// ---------------------------------------------------------------------------
extern "C" void kernel_launch(void* const* d_in, const int* in_sizes, int n_in,
                              void* d_out, int out_size, void* d_ws, size_t ws_size,
                              hipStream_t stream)
{
  (void)in_sizes; (void)n_in; (void)out_size; (void)ws_size;
  const int*   seq  = (const int*)d_in[0];
  // d_in[1] = enc_out : unused by the reference math
  const float* ench = (const float*)d_in[2];
  const float* encc = (const float*)d_in[3];
  const float* emb  = (const float*)d_in[4];
  const float* Wih  = (const float*)d_in[5];
  const float* Whh  = (const float*)d_in[6];
  const float* bih  = (const float*)d_in[7];
  const float* bhh  = (const float*)d_in[8];
  float* out = (float*)d_out;

  char* ws = (char*)d_ws;
  float*    cgb  = (float*)ws;
  unsigned* ctr  = (unsigned*)(ws + 262144);
  uint16_t* eg   = (uint16_t*)(ws + 262400);
  uint16_t* hbuf = (uint16_t*)(ws + 262400 + (size_t)67108864);

  k_const<<<dim3(256),  dim3(256), 0, stream>>>(Whh, ench, bih, bhh, cgb, ctr);
  k_emb  <<<dim3(4096), dim3(256), 0, stream>>>(seq, emb, Wih, cgb, eg);
  k_scan <<<dim3(GWG),  dim3(128), 0, stream>>>(Wih, encc, eg, hbuf, out, ctr);
}

// Round 3
// 3688.334 us; speedup vs baseline: 1.0081x; 1.0081x over previous
//
#include <hip/hip_runtime.h>
#include <stdint.h>

// Problem constants (DecoderLSTM): VOCAB=50257, E=H=512, B=32, S=512
// ALL float tensors are fp32; sequence is int32. Internal bf16 MFMA; fp32 out.
#define EDIM  512
#define HDIM  512
#define BSZ   32
#define SLEN  512
#define GDIM  2048   // 4*H
#define GWG   32     // number of scan workgroups (h-column split)

typedef __bf16 bf16x8 __attribute__((ext_vector_type(8)));
typedef float  f32x4  __attribute__((ext_vector_type(4)));

__device__ __forceinline__ uint16_t f2bf(float f) {
  union { float f; uint32_t i; } v; v.f = f;
  uint32_t r = v.i + 0x7FFFu + ((v.i >> 16) & 1u);  // RNE
  return (uint16_t)(r >> 16);
}
__device__ __forceinline__ float bf2f(uint32_t u) {
  union { uint32_t i; float f; } v; v.i = u << 16; return v.f;
}
union BF8 { uint16_t u[8]; uint4 v; bf16x8 b; unsigned long long q[2]; };
union BF4 { uint16_t u[4]; unsigned long long q; };
__device__ __forceinline__ uint4 pack8(float4 lo, float4 hi) {
  BF8 r;
  r.u[0] = f2bf(lo.x); r.u[1] = f2bf(lo.y); r.u[2] = f2bf(lo.z); r.u[3] = f2bf(lo.w);
  r.u[4] = f2bf(hi.x); r.u[5] = f2bf(hi.y); r.u[6] = f2bf(hi.z); r.u[7] = f2bf(hi.w);
  return r.v;
}
__device__ __forceinline__ float sigm(float x) { return 1.0f / (1.0f + __expf(-x)); }
__device__ __forceinline__ float tanh_(float x) {
  float ax = fabsf(x);
  float e  = __expf(2.0f * ax);          // overflow-safe: e=inf -> t=1
  float t  = 1.0f - 2.0f / (e + 1.0f);
  return copysignf(t, x);
}

// ---------------------------------------------------------------------------
// K1: const[g][b] = sum_k W_hh[g][k]*h0[b][k] + b_ih[g] + b_hh[g] (fp32);
// zeroes the barrier counter (plain store: kernel-end writeback makes it
// visible to k_scan's LLC-direct atomics before k_scan starts, stream order).
// ---------------------------------------------------------------------------
__global__ __launch_bounds__(256) void k_const(
    const float* __restrict__ Whh, const float* __restrict__ h0,
    const float* __restrict__ bih, const float* __restrict__ bhh,
    float* __restrict__ cgb, unsigned* __restrict__ ctr)
{
  int idx = blockIdx.x * 256 + threadIdx.x;        // 2048*32 = 65536
  if (idx == 0) *ctr = 0u;
  int g = idx >> 5, b = idx & 31;
  const float4* w4 = (const float4*)(Whh + (size_t)g * HDIM);
  const float4* h4 = (const float4*)(h0  + (size_t)b * HDIM);
  float acc = 0.f;
  #pragma unroll 8
  for (int k = 0; k < HDIM / 4; k++) {
    float4 a = w4[k], c = h4[k];
    acc += a.x * c.x + a.y * c.y + a.z * c.z + a.w * c.w;
  }
  acc += bih[g] + bhh[g];
  cgb[idx] = acc;   // layout [g][b]
}

// ---------------------------------------------------------------------------
// K2: eg[s][b][g] (bf16) = sum_e emb[seq[b][s]][e] * W_ih[g][e] + const[g][b]
// Per WG: 64 gate rows (bf16, frag-order, 64KB LDS) x 4 s values.
// MFMA 16x16x32_bf16: A = W_e chunk (M=g), B = gathered emb rows (N=b).
// ---------------------------------------------------------------------------
__global__ __launch_bounds__(256) void k_emb(
    const int* __restrict__ seq, const float* __restrict__ emb,
    const float* __restrict__ Wih, const float* __restrict__ cgb,
    uint16_t* __restrict__ eg)
{
  __shared__ uint4 wlds[4096];   // 64KB bf16, frag-order: [T=n>>4][kc][nl=n&15][q]
  const int tid = threadIdx.x;
  const int gc  = blockIdx.x & 31;   // 32 g-chunks of 64 rows
  const int sc  = blockIdx.x >> 5;   // 128 s-chunks of 4
  const int g0  = gc * 64, s0 = sc * 4;

  for (int i = tid; i < 64 * 64; i += 256) {       // 64 rows x 64 8-elem chunks
    int n = i >> 6, c = i & 63;
    const float* wp = Wih + (size_t)(g0 + n) * 1024 + c * 8;   // W_e = W_ih[:, :512]
    float4 lo = *(const float4*)(wp);
    float4 hi = *(const float4*)(wp + 4);
    wlds[(((n >> 4) * 16 + (c >> 2)) << 6) + ((n & 15) << 2) + (c & 3)] = pack8(lo, hi);
  }
  __syncthreads();

  const int lane = tid & 63, w = tid >> 6;
  const int q = lane >> 4, nl = lane & 15;
  const int Nt  = w & 1;            // b-tile
  const int Mt0 = (w >> 1) * 2;     // g-tile pair {Mt0, Mt0+1}
  const int bcol = Nt * 16 + nl;

  float c0i[4], c1i[4];             // baked const, fixed across s
  #pragma unroll
  for (int r = 0; r < 4; r++) {
    c0i[r] = cgb[(g0 + (Mt0    ) * 16 + q * 4 + r) * 32 + bcol];
    c1i[r] = cgb[(g0 + (Mt0 + 1) * 16 + q * 4 + r) * 32 + bcol];
  }

  for (int si = 0; si < 4; si++) {
    int s = s0 + si;
    int rowi = seq[bcol * SLEN + s];                 // gather index for this lane's b
    const float* brow = emb + (size_t)rowi * EDIM + q * 8;
    f32x4 acc0, acc1;
    #pragma unroll
    for (int r = 0; r < 4; r++) { acc0[r] = c0i[r]; acc1[r] = c1i[r]; }
    #pragma unroll 4
    for (int kc = 0; kc < 16; kc++) {
      float4 blo = *(const float4*)(brow + kc * 32);
      float4 bhi = *(const float4*)(brow + kc * 32 + 4);
      BF8 bf; bf.v = pack8(blo, bhi);
      BF8 a0; a0.v = wlds[(((Mt0    ) * 16 + kc) << 6) + (nl << 2) + q];
      BF8 a1; a1.v = wlds[(((Mt0 + 1) * 16 + kc) << 6) + (nl << 2) + q];
      acc0 = __builtin_amdgcn_mfma_f32_16x16x32_bf16(a0.b, bf.b, acc0, 0, 0, 0);
      acc1 = __builtin_amdgcn_mfma_f32_16x16x32_bf16(a1.b, bf.b, acc1, 0, 0, 0);
    }
    #pragma unroll
    for (int r = 0; r < 4; r++) {
      int m0 = (Mt0    ) * 16 + q * 4 + r;
      int m1 = (Mt0 + 1) * 16 + q * 4 + r;
      eg[((size_t)s * 32 + bcol) * GDIM + g0 + m0] = f2bf(acc0[r]);   // [s][b][g]
      eg[((size_t)s * 32 + bcol) * GDIM + g0 + m1] = f2bf(acc1[r]);
    }
  }
}

// ---------------------------------------------------------------------------
// K3: sequential scan, transposed MFMA orientation: A = W_h slice (LDS),
// B = h_{t-1} (LLC-direct atomic u64), C[j][b]. WG wg owns j in [wg*16,+16)
// for all 4 gates and all 32 batches (wave w = batch half w*16..+15).
// Lane (q,nl) of wave w owns (j = j0+q*4+r, b = w*16+nl) -> h store is ONE
// u64 (4 consecutive j bf16), out store is ONE float4. No release/acquire
// cache maintenance: h + ctr use sc0sc1 (LLC) accesses; ordering =
// s_waitcnt vmcnt(0) + __syncthreads before the relaxed add.
// ---------------------------------------------------------------------------
__global__ __launch_bounds__(128) void k_scan(
    const float* __restrict__ Wih, const float* __restrict__ c0,
    const uint16_t* __restrict__ eg, unsigned long long* __restrict__ hbuf,
    float* __restrict__ out, unsigned* __restrict__ ctr)
{
  __shared__ uint4 wlds[4096];   // 64KB
  const int tid = threadIdx.x;
  const int wg  = blockIdx.x;
  const int j0  = wg * 16;

  // Stage W_h slice: row n: gate=n>>4, jj=n&15 -> W_ih row gate*512+j0+jj, cols [512,1024)
  for (int i = tid; i < 64 * 64; i += 128) {
    int n = i >> 6, c = i & 63;
    int grow = (n >> 4) * HDIM + j0 + (n & 15);
    const float* wp = Wih + (size_t)grow * 1024 + 512 + c * 8;
    float4 lo = *(const float4*)(wp);
    float4 hi = *(const float4*)(wp + 4);
    wlds[(((n >> 4) * 16 + (c >> 2)) << 6) + ((n & 15) << 2) + (c & 3)] = pack8(lo, hi);
  }

  const int lane = tid & 63, w = tid >> 6;   // w = batch half (N-tile)
  const int q = lane >> 4, nl = lane & 15;
  const int b  = w * 16 + nl;                // owned batch (C col)
  const int jq = j0 + q * 4;                 // owned j's: jq..jq+3 (C rows)
  float c0r[4];
  #pragma unroll
  for (int r = 0; r < 4; r++) c0r[r] = c0[(size_t)b * HDIM + jq + r];
  __syncthreads();

  for (int t = 0; t < SLEN; t++) {
    // eg prefetch (plain cached loads; written by k_emb, stream-ordered):
    // in flight during the barrier spin.
    ushort4 egv[4];
    #pragma unroll
    for (int nt = 0; nt < 4; nt++)
      egv[nt] = *(const ushort4*)(eg + ((size_t)t * 32 + b) * GDIM + nt * HDIM + jq);

    if (t > 0) {
      if (tid == 0) {
        unsigned target = (unsigned)(GWG * t);
        while (__hip_atomic_load(ctr, __ATOMIC_RELAXED, __HIP_MEMORY_SCOPE_AGENT) < target) {}
      }
      __syncthreads();
    }

    f32x4 acc[4];
    #pragma unroll
    for (int nt = 0; nt < 4; nt++) {
      acc[nt][0] = bf2f(egv[nt].x); acc[nt][1] = bf2f(egv[nt].y);
      acc[nt][2] = bf2f(egv[nt].z); acc[nt][3] = bf2f(egv[nt].w);
    }

    if (t > 0) {
      // B-frag: h[b][k = kc*32 + q*8 .. +8]  (u64 idx: b*128 + kc*8 + q*2)
      const unsigned long long* hp = hbuf + ((t - 1) & 1) * (BSZ * HDIM / 4)
                                   + (size_t)b * 128 + q * 2;
      #pragma unroll 4
      for (int kc = 0; kc < 16; kc++) {
        BF8 hf;
        hf.q[0] = __hip_atomic_load(hp + kc * 8,     __ATOMIC_RELAXED, __HIP_MEMORY_SCOPE_AGENT);
        hf.q[1] = __hip_atomic_load(hp + kc * 8 + 1, __ATOMIC_RELAXED, __HIP_MEMORY_SCOPE_AGENT);
        #pragma unroll
        for (int nt = 0; nt < 4; nt++) {
          BF8 af; af.v = wlds[((nt * 16 + kc) << 6) + (nl << 2) + q];
          acc[nt] = __builtin_amdgcn_mfma_f32_16x16x32_bf16(af.b, hf.b, acc[nt], 0, 0, 0);
        }
      }
    }

    float4 ov;
    BF4 hb;
    {
      float i0 = sigm(acc[0][0]), f0 = sigm(acc[1][0]), g0v = tanh_(acc[2][0]), o0 = sigm(acc[3][0]);
      float i1 = sigm(acc[0][1]), f1 = sigm(acc[1][1]), g1v = tanh_(acc[2][1]), o1 = sigm(acc[3][1]);
      float i2 = sigm(acc[0][2]), f2 = sigm(acc[1][2]), g2v = tanh_(acc[2][2]), o2 = sigm(acc[3][2]);
      float i3 = sigm(acc[0][3]), f3 = sigm(acc[1][3]), g3v = tanh_(acc[2][3]), o3 = sigm(acc[3][3]);
      ov.x = o0 * tanh_(f0 * c0r[0] + i0 * g0v);   // cell NOT carried: always c0
      ov.y = o1 * tanh_(f1 * c0r[1] + i1 * g1v);
      ov.z = o2 * tanh_(f2 * c0r[2] + i2 * g2v);
      ov.w = o3 * tanh_(f3 * c0r[3] + i3 * g3v);
      hb.u[0] = f2bf(ov.x); hb.u[1] = f2bf(ov.y); hb.u[2] = f2bf(ov.z); hb.u[3] = f2bf(ov.w);
    }
    // out[b][t][jq..jq+3] — normal cached store (flushed at kernel end)
    *(float4*)(out + (size_t)b * (SLEN * HDIM) + (size_t)t * HDIM + jq) = ov;
    // h ping-pong: ONE u64 LLC-direct store (4 consecutive j)
    __hip_atomic_store(hbuf + (t & 1) * (BSZ * HDIM / 4) + (size_t)b * 128 + (jq >> 2),
                       hb.q, __ATOMIC_RELAXED, __HIP_MEMORY_SCOPE_AGENT);

    __builtin_amdgcn_s_waitcnt(0x0F70);  // vmcnt(0): h stores acked at LLC
    __syncthreads();                     // all waves drained
    if (tid == 0)
      __hip_atomic_fetch_add(ctr, 1u, __ATOMIC_RELAXED, __HIP_MEMORY_SCOPE_AGENT);
  }
}

// ---------------------------------------------------------------------------
// Workspace (~67.6 MB):
//   [0,       262144)   const[g][b] f32
//   [262144,  262148)   barrier counter
//   [262400, +64MiB)    eg[s][b][g] bf16 (const baked in)
//   then 2 x 32KB h ping-pong (bf16, u64-accessed)
// ---------------------------------------------------------------------------
extern "C" void kernel_launch(void* const* d_in, const int* in_sizes, int n_in,
                              void* d_out, int out_size, void* d_ws, size_t ws_size,
                              hipStream_t stream)
{
  (void)in_sizes; (void)n_in; (void)out_size; (void)ws_size;
  const int*   seq  = (const int*)d_in[0];
  // d_in[1] = enc_out : unused by the reference math
  const float* ench = (const float*)d_in[2];
  const float* encc = (const float*)d_in[3];
  const float* emb  = (const float*)d_in[4];
  const float* Wih  = (const float*)d_in[5];
  const float* Whh  = (const float*)d_in[6];
  const float* bih  = (const float*)d_in[7];
  const float* bhh  = (const float*)d_in[8];
  float* out = (float*)d_out;

  char* ws = (char*)d_ws;
  float*    cgb  = (float*)ws;
  unsigned* ctr  = (unsigned*)(ws + 262144);
  uint16_t* eg   = (uint16_t*)(ws + 262400);
  unsigned long long* hbuf = (unsigned long long*)(ws + 262400 + (size_t)67108864);

  k_const<<<dim3(256),  dim3(256), 0, stream>>>(Whh, ench, bih, bhh, cgb, ctr);
  k_emb  <<<dim3(4096), dim3(256), 0, stream>>>(seq, emb, Wih, cgb, eg);
  k_scan <<<dim3(GWG),  dim3(128), 0, stream>>>(Wih, encc, eg, hbuf, out, ctr);
}